// Round 1
// baseline (53.368 us; speedup 1.0000x reference)
//
#include <hip/hip_runtime.h>

// out[s,d,b,j] = log( sum_i exp(x[s,d,b,i]) * acc[s,d,i,j] ) - log( sum_i acc[s,d,i,j] )
// 256 batched 256x256x256 GEMMs in linear space, bf16 MFMA, fp32 accumulate.

#define NSC 32
#define NDC 8
#define NB  256
#define NI  256
#define NJ  256

typedef __attribute__((ext_vector_type(8))) short bf16x8;
typedef __attribute__((ext_vector_type(4))) float f32x4;

__device__ __forceinline__ unsigned short f2bf(float f) {
  // round-to-nearest-even; inputs are positive normals (no NaN/Inf)
  unsigned int u = __float_as_uint(f);
  u += 0x7FFFu + ((u >> 16) & 1u);
  return (unsigned short)(u >> 16);
}

__global__ __launch_bounds__(512, 2)
void densesum_kernel(const float* __restrict__ x,
                     const float* __restrict__ acc,
                     float* __restrict__ out) {
  const int sd = blockIdx.x;                 // s*NDC + d
  const float* xb = x   + (size_t)sd * NB * NI;
  const float* ab = acc + (size_t)sd * NI * NJ;
  float*       ob = out + (size_t)sd * NB * NJ;

  // A = exp(x) [256 b][64 k] bf16 ; B^T = acc^T [256 j][64 k] bf16.
  // Rows are 128B -> XOR-swizzle byte ^= ((row&7)<<4) for conflict-free ds_read_b128.
  __shared__ unsigned short As[NB * 64];
  __shared__ unsigned short Bs[NJ * 64];
  __shared__ float colpart[8 * NJ];
  __shared__ float logS[NJ];

  const int tid  = threadIdx.x;
  const int lane = tid & 63;
  const int wid  = tid >> 6;      // 8 waves
  const int wr   = wid >> 2;      // 0..1  (128-row strip)
  const int wc   = wid & 3;       // 0..3  (64-col strip)
  const int l15  = lane & 15;
  const int lk   = lane >> 4;     // 0..3

  f32x4 C[8][4];
  #pragma unroll
  for (int m = 0; m < 8; ++m)
    #pragma unroll
    for (int n = 0; n < 4; ++n)
      C[m][n] = (f32x4){0.f, 0.f, 0.f, 0.f};

  float bsum0 = 0.f, bsum1 = 0.f, bsum2 = 0.f, bsum3 = 0.f;

  for (int kc = 0; kc < 4; ++kc) {
    const int i0 = kc * 64;

    // ---- stage A: exp(x) -> bf16, row-major [b][k]
    #pragma unroll
    for (int it = 0; it < 8; ++it) {
      int q  = tid + it * 512;              // 0..4095 quads
      int b  = q >> 4;                      // 0..255
      int c0 = (q & 15) * 4;                // 0..60
      const float4 xv = *reinterpret_cast<const float4*>(xb + (size_t)b * NI + i0 + c0);
      ushort4 h;
      h.x = f2bf(__expf(xv.x));
      h.y = f2bf(__expf(xv.y));
      h.z = f2bf(__expf(xv.z));
      h.w = f2bf(__expf(xv.w));
      *reinterpret_cast<ushort4*>(&As[b * 64 + (c0 ^ ((b & 7) << 3))]) = h;
    }

    // ---- stage B^T: acc -> bf16 transposed [j][k]; fuse fp32 column sums
    #pragma unroll
    for (int it = 0; it < 8; ++it) {
      int q = tid + it * 512;
      int k = q >> 6;                       // 0..63
      int j = (q & 63) * 4;                 // 0..252
      const float4 av = *reinterpret_cast<const float4*>(ab + (size_t)(i0 + k) * NJ + j);
      bsum0 += av.x; bsum1 += av.y; bsum2 += av.z; bsum3 += av.w;
      Bs[(j + 0) * 64 + (k ^ (((j + 0) & 7) << 3))] = f2bf(av.x);
      Bs[(j + 1) * 64 + (k ^ (((j + 1) & 7) << 3))] = f2bf(av.y);
      Bs[(j + 2) * 64 + (k ^ (((j + 2) & 7) << 3))] = f2bf(av.z);
      Bs[(j + 3) * 64 + (k ^ (((j + 3) & 7) << 3))] = f2bf(av.w);
    }
    __syncthreads();

    // ---- MFMA over this K-chunk (2 k-steps of 32)
    #pragma unroll
    for (int ks = 0; ks < 2; ++ks) {
      const int k0 = ks * 32 + 8 * lk;
      bf16x8 af[8], bfr[4];
      #pragma unroll
      for (int m = 0; m < 8; ++m) {
        int row = wr * 128 + m * 16 + l15;
        af[m] = *reinterpret_cast<const bf16x8*>(&As[row * 64 + (k0 ^ ((row & 7) << 3))]);
      }
      #pragma unroll
      for (int n = 0; n < 4; ++n) {
        int row = wc * 64 + n * 16 + l15;
        bfr[n] = *reinterpret_cast<const bf16x8*>(&Bs[row * 64 + (k0 ^ ((row & 7) << 3))]);
      }
      #pragma unroll
      for (int m = 0; m < 8; ++m)
        #pragma unroll
        for (int n = 0; n < 4; ++n)
          C[m][n] = __builtin_amdgcn_mfma_f32_16x16x32_bf16(af[m], bfr[n], C[m][n], 0, 0, 0);
    }
    __syncthreads();
  }

  // ---- reduce per-thread column partials -> logS[j]
  {
    int j4 = (lane) * 4;
    colpart[wid * NJ + j4 + 0] = bsum0;
    colpart[wid * NJ + j4 + 1] = bsum1;
    colpart[wid * NJ + j4 + 2] = bsum2;
    colpart[wid * NJ + j4 + 3] = bsum3;
  }
  __syncthreads();
  if (tid < NJ) {
    float s = 0.f;
    #pragma unroll
    for (int c = 0; c < 8; ++c) s += colpart[c * NJ + tid];
    logS[tid] = __logf(s);
  }
  __syncthreads();

  // ---- epilogue: out[b][j] = log(C) - logS[j]
  // C/D layout (16x16): col = lane&15, row = (lane>>4)*4 + reg
  #pragma unroll
  for (int m = 0; m < 8; ++m) {
    int b0 = wr * 128 + m * 16 + lk * 4;
    #pragma unroll
    for (int n = 0; n < 4; ++n) {
      int j = wc * 64 + n * 16 + l15;
      float ls = logS[j];
      #pragma unroll
      for (int r = 0; r < 4; ++r) {
        ob[(size_t)(b0 + r) * NJ + j] = __logf(C[m][n][r]) - ls;
      }
    }
  }
}

extern "C" void kernel_launch(void* const* d_in, const int* in_sizes, int n_in,
                              void* d_out, int out_size, void* d_ws, size_t ws_size,
                              hipStream_t stream) {
  const float* x   = (const float*)d_in[0];
  const float* acc = (const float*)d_in[1];
  float* out = (float*)d_out;
  hipLaunchKernelGGL(densesum_kernel, dim3(NSC * NDC), dim3(512), 0, stream, x, acc, out);
}